// Round 2
// baseline (319.499 us; speedup 1.0000x reference)
//
#include <hip/hip_runtime.h>
#include <math.h>

// ---------------------------------------------------------------------------
// YOLOv5-style loss, 3 layers, fp32.
// R2: replace the scattered per-(entry,class) gather (97 MB of wasted cache
// lines @1 TB/s) with a coalesced scan of channels 4..84:
//   cls = sum_cells cnt[cell] * sum_c bce0(x)  -  sum_entries x[tcls]
//   obj = sum_cells bce0(x4)  -  sum_{winner cells} x4 * clip(iou,0)
// cnt[cell] = multiplicity of entries at that cell (duplicates share logits).
// Scan skips 64B pred lines where all 16 cnt are zero.
// ---------------------------------------------------------------------------

#define EPS 1e-7f
#define BS 16
#define NA 3
#define NC 80

struct Layer {
    const float* pred;
    const int*   b;
    const int*   a;
    const int*   gj;
    const int*   gi;
    const int*   tcls;
    const float* tbox;
    const float* anc;
    unsigned int* winner;   // [48*g*g] cells, 0 = empty else entry_idx+1
    unsigned int* cnt;      // [48*g*g] entry multiplicity per cell
    float*        iou;      // [n] CIoU per entry
    int g;
    int n;
};

struct Args {
    Layer L[3];
    int cum0;   // blocks of layer 0
    int cum1;   // blocks of layers 0+1
};

__device__ __forceinline__ int pick_layer(const Args& A, int& lb) {
    int bid = blockIdx.x;
    if (bid < A.cum0) { lb = bid; return 0; }
    if (bid < A.cum1) { lb = bid - A.cum0; return 1; }
    lb = bid - A.cum1; return 2;
}

// reduce two independent sums across a 256-thread block
__device__ __forceinline__ void block_reduce256_2(float& a, float& b) {
    #pragma unroll
    for (int o = 32; o > 0; o >>= 1) {
        a += __shfl_down(a, o, 64);
        b += __shfl_down(b, o, 64);
    }
    __shared__ float sma[4], smb[4];
    int lane = threadIdx.x & 63;
    int wid  = threadIdx.x >> 6;
    if (lane == 0) { sma[wid] = a; smb[wid] = b; }
    __syncthreads();
    if (threadIdx.x == 0) {
        a = sma[0] + sma[1] + sma[2] + sma[3];
        b = smb[0] + smb[1] + smb[2] + smb[3];
    }
}

__device__ __forceinline__ float bce0(float x) {
    // bce_with_logits(x, 0) = max(x,0) + log1p(exp(-|x|))
    return fmaxf(x, 0.f) + log1pf(expf(-fabsf(x)));
}

// --- kernel 1: per-entry CIoU + box loss + winner/cnt scatter + tcls gather -
__global__ void entry_kernel(Args A, float* acc) {
    int lb; int layer = pick_layer(A, lb);
    const Layer L = A.L[layer];
    int j = lb * 256 + (int)threadIdx.x;
    float box_c = 0.f;
    float neg_c = 0.f;    // x[tcls] to subtract from cls sum
    if (j < L.n) {
        int b  = L.b[j],  a  = L.a[j];
        int gy = L.gj[j], gx = L.gi[j];
        int g = L.g, gg = g * g;
        int q = b * NA + a;
        const float* base = L.pred + ((size_t)(q * 85) * gg + (size_t)gy * g + gx);
        float px = base[0];
        float py = base[gg];
        float pw = base[2 * (size_t)gg];
        float ph = base[3 * (size_t)gg];
        // decode
        float cx = 2.f / (1.f + expf(-px)) - 0.5f;
        float cy = 2.f / (1.f + expf(-py)) - 0.5f;
        float sw = 2.f / (1.f + expf(-pw));
        float sh = 2.f / (1.f + expf(-ph));
        float bw = sw * sw * L.anc[2 * j];
        float bh = sh * sh * L.anc[2 * j + 1];
        float fg = (float)g;
        float tx = L.tbox[4 * j + 0] * fg - (float)gx;
        float ty = L.tbox[4 * j + 1] * fg - (float)gy;
        float tw = L.tbox[4 * j + 2] * fg;
        float th = L.tbox[4 * j + 3] * fg;
        // CIoU
        float b1x1 = cx - bw * 0.5f, b1x2 = cx + bw * 0.5f;
        float b1y1 = cy - bh * 0.5f, b1y2 = cy + bh * 0.5f;
        float b2x1 = tx - tw * 0.5f, b2x2 = tx + tw * 0.5f;
        float b2y1 = ty - th * 0.5f, b2y2 = ty + th * 0.5f;
        float iw = fminf(b1x2, b2x2) - fmaxf(b1x1, b2x1);
        float ih = fminf(b1y2, b2y2) - fmaxf(b1y1, b2y1);
        float inter = fmaxf(iw, 0.f) * fmaxf(ih, 0.f);
        float w1 = b1x2 - b1x1, h1 = b1y2 - b1y1 + EPS;
        float w2 = b2x2 - b2x1, h2 = b2y2 - b2y1 + EPS;
        float uni = w1 * h1 + w2 * h2 - inter + EPS;
        float iou = inter / uni;
        float cw  = fmaxf(b1x2, b2x2) - fminf(b1x1, b2x1);
        float chh = fmaxf(b1y2, b2y2) - fminf(b1y1, b2y1);
        float c2  = cw * cw + chh * chh + EPS;
        float dx = b2x1 + b2x2 - b1x1 - b1x2;
        float dy = b2y1 + b2y2 - b1y1 - b1y2;
        float rho2 = (dx * dx + dy * dy) * 0.25f;
        float dv = atanf(w2 / h2) - atanf(w1 / h1);
        float v = (4.f / (float)(M_PI * M_PI)) * dv * dv;
        float alpha = v / (v - iou + (1.f + EPS));
        float ciou = iou - (rho2 / c2 + v * alpha);
        L.iou[j] = ciou;
        int cell = q * gg + gy * g + gx;
        atomicMax(&L.winner[cell], (unsigned int)(j + 1));
        atomicAdd(&L.cnt[cell], 1u);
        box_c = 1.f - ciou;
        // class positive term: bce(x,1) = bce(x,0) - x  -> subtract x[tcls]
        neg_c = base[(size_t)(5 + L.tcls[j]) * gg];
    }
    block_reduce256_2(box_c, neg_c);
    if (threadIdx.x == 0) {
        atomicAdd(&acc[0 + layer], box_c);
        atomicAdd(&acc[6 + layer], -neg_c);
    }
}

// --- kernel 2: coalesced scan of channels 4..84 of every (b,a) plane --------
// 16 floats per thread (aligned: gg % 16 == 0), per-layer block ranges.
__global__ void scan_kernel(Args A, float* acc) {
    int lb; int layer = pick_layer(A, lb);
    const Layer L = A.L[layer];
    int gg = L.g * L.g;
    int total = BS * NA * 81 * gg;          // elements scanned this layer
    int idx = (lb * 256 + (int)threadIdx.x) * 16;
    float obj_s = 0.f, cls_s = 0.f;
    if (idx < total) {
        int p = idx / gg;                   // plane: q*81 + r, channel c = 4+r
        int e = idx - p * gg;
        int q = p / 81;
        int r = p - q * 81;
        int cell = q * gg + e;
        const float4* px = (const float4*)(L.pred + (size_t)(q * 85 + 4 + r) * gg + e);
        if (r == 0) {
            // objectness plane
            const uint4* wv = (const uint4*)(L.winner + cell);
            #pragma unroll
            for (int v = 0; v < 4; ++v) {
                float4 x4 = px[v];
                uint4  w4 = wv[v];
                float xs[4] = {x4.x, x4.y, x4.z, x4.w};
                unsigned ws[4] = {w4.x, w4.y, w4.z, w4.w};
                #pragma unroll
                for (int k = 0; k < 4; ++k) {
                    float o = bce0(xs[k]);
                    if (ws[k]) o -= xs[k] * fmaxf(L.iou[ws[k] - 1], 0.f);
                    obj_s += o;
                }
            }
        } else {
            // class plane: weight by per-cell multiplicity, skip empty lines
            const uint4* cv = (const uint4*)(L.cnt + cell);
            uint4 c0 = cv[0], c1 = cv[1], c2 = cv[2], c3 = cv[3];
            unsigned any = c0.x | c0.y | c0.z | c0.w | c1.x | c1.y | c1.z | c1.w |
                           c2.x | c2.y | c2.z | c2.w | c3.x | c3.y | c3.z | c3.w;
            if (any) {
                unsigned cs[16] = {c0.x, c0.y, c0.z, c0.w, c1.x, c1.y, c1.z, c1.w,
                                   c2.x, c2.y, c2.z, c2.w, c3.x, c3.y, c3.z, c3.w};
                #pragma unroll
                for (int v = 0; v < 4; ++v) {
                    float4 x4 = px[v];
                    float xs[4] = {x4.x, x4.y, x4.z, x4.w};
                    #pragma unroll
                    for (int k = 0; k < 4; ++k) {
                        unsigned c = cs[4 * v + k];
                        if (c) cls_s += (float)c * bce0(xs[k]);
                    }
                }
            }
        }
    }
    block_reduce256_2(obj_s, cls_s);
    if (threadIdx.x == 0) {
        if (obj_s != 0.f) atomicAdd(&acc[3 + layer], obj_s);
        if (cls_s != 0.f) atomicAdd(&acc[6 + layer], cls_s);
    }
}

// --- kernel 3: combine ------------------------------------------------------
__global__ void final_kernel(const float* acc, float* out,
                             int n0, int n1, int n2,
                             int c0, int c1, int c2) {
    float box_l = acc[0] / (float)n0 + acc[1] / (float)n1 + acc[2] / (float)n2;
    float obj_l = 0.4f * acc[3] / (float)c0
                + 1.0f * acc[4] / (float)c1
                + 4.0f * acc[5] / (float)c2;
    float cls_l = acc[6] / ((float)n0 * NC)
                + acc[7] / ((float)n1 * NC)
                + acc[8] / ((float)n2 * NC);
    out[0] = 0.05f * box_l + 1.0f * obj_l + 0.5f * cls_l;
}

extern "C" void kernel_launch(void* const* d_in, const int* in_sizes, int n_in,
                              void* d_out, int out_size, void* d_ws, size_t ws_size,
                              hipStream_t stream) {
    (void)n_in; (void)out_size; (void)ws_size;
    char* ws = (char*)d_ws;

    Args A;
    int n[3], g[3], cells[3];
    size_t off = 64;                       // bytes 0..63: 9 float accumulators
    size_t winner_off[3], cnt_off[3], iou_off[3];

    for (int i = 0; i < 3; ++i) {
        n[i] = in_sizes[8 * i + 1];
        int gg = in_sizes[8 * i] / (BS * 255);
        int gv = (int)(sqrt((double)gg) + 0.5);
        g[i] = gv;
        cells[i] = BS * NA * gv * gv;
        winner_off[i] = off; off += (size_t)cells[i] * 4;
        cnt_off[i]    = off; off += (size_t)cells[i] * 4;
    }
    size_t zero_bytes = off;               // accumulators + winner + cnt
    for (int i = 0; i < 3; ++i) { iou_off[i] = off; off += (size_t)n[i] * 4; }

    for (int i = 0; i < 3; ++i) {
        Layer& L = A.L[i];
        L.pred = (const float*)d_in[8 * i + 0];
        L.b    = (const int*)  d_in[8 * i + 1];
        L.a    = (const int*)  d_in[8 * i + 2];
        L.gj   = (const int*)  d_in[8 * i + 3];
        L.gi   = (const int*)  d_in[8 * i + 4];
        L.tbox = (const float*)d_in[8 * i + 5];
        L.tcls = (const int*)  d_in[8 * i + 6];
        L.anc  = (const float*)d_in[8 * i + 7];
        L.winner = (unsigned int*)(ws + winner_off[i]);
        L.cnt    = (unsigned int*)(ws + cnt_off[i]);
        L.iou    = (float*)(ws + iou_off[i]);
        L.g = g[i];
        L.n = n[i];
    }
    float* acc = (float*)ws;

    hipMemsetAsync(d_ws, 0, zero_bytes, stream);

    // entry kernel: CIoU + scatter winner/cnt + tcls gather
    {
        int b0 = (n[0] + 255) / 256, b1 = (n[1] + 255) / 256, b2 = (n[2] + 255) / 256;
        A.cum0 = b0; A.cum1 = b0 + b1;
        entry_kernel<<<b0 + b1 + b2, 256, 0, stream>>>(A, acc);
    }
    // scan kernel: obj + cls in one coalesced pass (16 floats/thread)
    {
        const int grain = 256 * 16;
        int t0 = BS * NA * 81 * g[0] * g[0];
        int t1 = BS * NA * 81 * g[1] * g[1];
        int t2 = BS * NA * 81 * g[2] * g[2];
        int b0 = (t0 + grain - 1) / grain;
        int b1 = (t1 + grain - 1) / grain;
        int b2 = (t2 + grain - 1) / grain;
        A.cum0 = b0; A.cum1 = b0 + b1;
        scan_kernel<<<b0 + b1 + b2, 256, 0, stream>>>(A, acc);
    }
    final_kernel<<<1, 1, 0, stream>>>(acc, (float*)d_out,
                                      n[0], n[1], n[2],
                                      cells[0], cells[1], cells[2]);
}

// Round 3
// 302.373 us; speedup vs baseline: 1.0566x; 1.0566x over previous
//
#include <hip/hip_runtime.h>
#include <math.h>

// ---------------------------------------------------------------------------
// YOLOv5-style loss, 3 layers, fp32.
// R3: scan kernel was VALU-bound (81% VALUBusy) on libm expf/log1pf (~40
// branchy instrs each, paid per-wave under divergence). Replace with HW
// transcendentals (v_exp_f32 / v_log_f32 via __builtin_amdgcn_*):
//   bce0(x) = max(x,0) + ln2 * log2(1 + 2^(-|x|*log2e))   (~7 VALU ops)
// and make the cls accumulation branchless (weight by cnt, cnt=0 adds 0).
// Memory skip on all-zero-cnt 64B granules retained.
// ---------------------------------------------------------------------------

#define EPS 1e-7f
#define BS 16
#define NA 3
#define NC 80

#define LOG2E 1.44269504088896340736f
#define LN2   0.69314718055994530942f

struct Layer {
    const float* pred;
    const int*   b;
    const int*   a;
    const int*   gj;
    const int*   gi;
    const int*   tcls;
    const float* tbox;
    const float* anc;
    unsigned int* winner;   // [48*g*g] cells, 0 = empty else entry_idx+1
    unsigned int* cnt;      // [48*g*g] entry multiplicity per cell
    float*        iou;      // [n] CIoU per entry
    int g;
    int n;
};

struct Args {
    Layer L[3];
    int cum0;   // blocks of layer 0
    int cum1;   // blocks of layers 0+1
};

__device__ __forceinline__ int pick_layer(const Args& A, int& lb) {
    int bid = blockIdx.x;
    if (bid < A.cum0) { lb = bid; return 0; }
    if (bid < A.cum1) { lb = bid - A.cum0; return 1; }
    lb = bid - A.cum1; return 2;
}

// reduce two independent sums across a 256-thread block
__device__ __forceinline__ void block_reduce256_2(float& a, float& b) {
    #pragma unroll
    for (int o = 32; o > 0; o >>= 1) {
        a += __shfl_down(a, o, 64);
        b += __shfl_down(b, o, 64);
    }
    __shared__ float sma[4], smb[4];
    int lane = threadIdx.x & 63;
    int wid  = threadIdx.x >> 6;
    if (lane == 0) { sma[wid] = a; smb[wid] = b; }
    __syncthreads();
    if (threadIdx.x == 0) {
        a = sma[0] + sma[1] + sma[2] + sma[3];
        b = smb[0] + smb[1] + smb[2] + smb[3];
    }
}

// bce_with_logits(x, 0) via HW transcendentals: branchless, ~7 VALU ops
__device__ __forceinline__ float bce0(float x) {
    float t = __builtin_amdgcn_exp2f(-fabsf(x) * LOG2E);   // exp(-|x|)
    return fmaxf(x, 0.f) + LN2 * __builtin_amdgcn_logf(1.f + t);
}

// sigmoid via HW exp2 + rcp
__device__ __forceinline__ float fsigmoid(float x) {
    float e = __builtin_amdgcn_exp2f(-x * LOG2E);
    return __builtin_amdgcn_rcpf(1.f + e);
}

// --- kernel 1: per-entry CIoU + box loss + winner/cnt scatter + tcls gather -
__global__ void entry_kernel(Args A, float* acc) {
    int lb; int layer = pick_layer(A, lb);
    const Layer L = A.L[layer];
    int j = lb * 256 + (int)threadIdx.x;
    float box_c = 0.f;
    float neg_c = 0.f;    // x[tcls] to subtract from cls sum
    if (j < L.n) {
        int b  = L.b[j],  a  = L.a[j];
        int gy = L.gj[j], gx = L.gi[j];
        int g = L.g, gg = g * g;
        int q = b * NA + a;
        const float* base = L.pred + ((size_t)(q * 85) * gg + (size_t)gy * g + gx);
        float px = base[0];
        float py = base[gg];
        float pw = base[2 * (size_t)gg];
        float ph = base[3 * (size_t)gg];
        // decode
        float cx = 2.f * fsigmoid(px) - 0.5f;
        float cy = 2.f * fsigmoid(py) - 0.5f;
        float sw = 2.f * fsigmoid(pw);
        float sh = 2.f * fsigmoid(ph);
        float bw = sw * sw * L.anc[2 * j];
        float bh = sh * sh * L.anc[2 * j + 1];
        float fg = (float)g;
        float tx = L.tbox[4 * j + 0] * fg - (float)gx;
        float ty = L.tbox[4 * j + 1] * fg - (float)gy;
        float tw = L.tbox[4 * j + 2] * fg;
        float th = L.tbox[4 * j + 3] * fg;
        // CIoU
        float b1x1 = cx - bw * 0.5f, b1x2 = cx + bw * 0.5f;
        float b1y1 = cy - bh * 0.5f, b1y2 = cy + bh * 0.5f;
        float b2x1 = tx - tw * 0.5f, b2x2 = tx + tw * 0.5f;
        float b2y1 = ty - th * 0.5f, b2y2 = ty + th * 0.5f;
        float iw = fminf(b1x2, b2x2) - fmaxf(b1x1, b2x1);
        float ih = fminf(b1y2, b2y2) - fmaxf(b1y1, b2y1);
        float inter = fmaxf(iw, 0.f) * fmaxf(ih, 0.f);
        float w1 = b1x2 - b1x1, h1 = b1y2 - b1y1 + EPS;
        float w2 = b2x2 - b2x1, h2 = b2y2 - b2y1 + EPS;
        float uni = w1 * h1 + w2 * h2 - inter + EPS;
        float iou = inter / uni;
        float cw  = fmaxf(b1x2, b2x2) - fminf(b1x1, b2x1);
        float chh = fmaxf(b1y2, b2y2) - fminf(b1y1, b2y1);
        float c2  = cw * cw + chh * chh + EPS;
        float dx = b2x1 + b2x2 - b1x1 - b1x2;
        float dy = b2y1 + b2y2 - b1y1 - b1y2;
        float rho2 = (dx * dx + dy * dy) * 0.25f;
        float dv = atanf(w2 / h2) - atanf(w1 / h1);
        float v = (4.f / (float)(M_PI * M_PI)) * dv * dv;
        float alpha = v / (v - iou + (1.f + EPS));
        float ciou = iou - (rho2 / c2 + v * alpha);
        L.iou[j] = ciou;
        int cell = q * gg + gy * g + gx;
        atomicMax(&L.winner[cell], (unsigned int)(j + 1));
        atomicAdd(&L.cnt[cell], 1u);
        box_c = 1.f - ciou;
        // class positive term: bce(x,1) = bce(x,0) - x  -> subtract x[tcls]
        neg_c = base[(size_t)(5 + L.tcls[j]) * gg];
    }
    block_reduce256_2(box_c, neg_c);
    if (threadIdx.x == 0) {
        atomicAdd(&acc[0 + layer], box_c);
        atomicAdd(&acc[6 + layer], -neg_c);
    }
}

// --- kernel 2: coalesced scan of channels 4..84 of every (b,a) plane --------
// 16 floats per thread (aligned: gg % 16 == 0), per-layer block ranges.
__global__ void scan_kernel(Args A, float* acc) {
    int lb; int layer = pick_layer(A, lb);
    const Layer L = A.L[layer];
    int gg = L.g * L.g;
    int total = BS * NA * 81 * gg;          // elements scanned this layer
    int idx = (lb * 256 + (int)threadIdx.x) * 16;
    float obj_s = 0.f, cls_s = 0.f;
    if (idx < total) {
        int p = idx / gg;                   // plane: q*81 + r, channel c = 4+r
        int e = idx - p * gg;
        int q = p / 81;
        int r = p - q * 81;
        int cell = q * gg + e;
        const float4* px = (const float4*)(L.pred + (size_t)(q * 85 + 4 + r) * gg + e);
        if (r == 0) {
            // objectness plane
            const uint4* wv = (const uint4*)(L.winner + cell);
            #pragma unroll
            for (int v = 0; v < 4; ++v) {
                float4 x4 = px[v];
                uint4  w4 = wv[v];
                float xs[4] = {x4.x, x4.y, x4.z, x4.w};
                unsigned ws[4] = {w4.x, w4.y, w4.z, w4.w};
                #pragma unroll
                for (int k = 0; k < 4; ++k) {
                    float o = bce0(xs[k]);
                    if (ws[k]) o -= xs[k] * fmaxf(L.iou[ws[k] - 1], 0.f);
                    obj_s += o;
                }
            }
        } else {
            // class plane: weight by per-cell multiplicity (branchless),
            // skip the pred line entirely when all 16 cnt are zero
            const uint4* cv = (const uint4*)(L.cnt + cell);
            uint4 c0 = cv[0], c1 = cv[1], c2 = cv[2], c3 = cv[3];
            unsigned any = c0.x | c0.y | c0.z | c0.w | c1.x | c1.y | c1.z | c1.w |
                           c2.x | c2.y | c2.z | c2.w | c3.x | c3.y | c3.z | c3.w;
            if (any) {
                unsigned cs[16] = {c0.x, c0.y, c0.z, c0.w, c1.x, c1.y, c1.z, c1.w,
                                   c2.x, c2.y, c2.z, c2.w, c3.x, c3.y, c3.z, c3.w};
                #pragma unroll
                for (int v = 0; v < 4; ++v) {
                    float4 x4 = px[v];
                    float xs[4] = {x4.x, x4.y, x4.z, x4.w};
                    #pragma unroll
                    for (int k = 0; k < 4; ++k) {
                        cls_s += (float)cs[4 * v + k] * bce0(xs[k]);
                    }
                }
            }
        }
    }
    block_reduce256_2(obj_s, cls_s);
    if (threadIdx.x == 0) {
        if (obj_s != 0.f) atomicAdd(&acc[3 + layer], obj_s);
        if (cls_s != 0.f) atomicAdd(&acc[6 + layer], cls_s);
    }
}

// --- kernel 3: combine ------------------------------------------------------
__global__ void final_kernel(const float* acc, float* out,
                             int n0, int n1, int n2,
                             int c0, int c1, int c2) {
    float box_l = acc[0] / (float)n0 + acc[1] / (float)n1 + acc[2] / (float)n2;
    float obj_l = 0.4f * acc[3] / (float)c0
                + 1.0f * acc[4] / (float)c1
                + 4.0f * acc[5] / (float)c2;
    float cls_l = acc[6] / ((float)n0 * NC)
                + acc[7] / ((float)n1 * NC)
                + acc[8] / ((float)n2 * NC);
    out[0] = 0.05f * box_l + 1.0f * obj_l + 0.5f * cls_l;
}

extern "C" void kernel_launch(void* const* d_in, const int* in_sizes, int n_in,
                              void* d_out, int out_size, void* d_ws, size_t ws_size,
                              hipStream_t stream) {
    (void)n_in; (void)out_size; (void)ws_size;
    char* ws = (char*)d_ws;

    Args A;
    int n[3], g[3], cells[3];
    size_t off = 64;                       // bytes 0..63: 9 float accumulators
    size_t winner_off[3], cnt_off[3], iou_off[3];

    for (int i = 0; i < 3; ++i) {
        n[i] = in_sizes[8 * i + 1];
        int gg = in_sizes[8 * i] / (BS * 255);
        int gv = (int)(sqrt((double)gg) + 0.5);
        g[i] = gv;
        cells[i] = BS * NA * gv * gv;
        winner_off[i] = off; off += (size_t)cells[i] * 4;
        cnt_off[i]    = off; off += (size_t)cells[i] * 4;
    }
    size_t zero_bytes = off;               // accumulators + winner + cnt
    for (int i = 0; i < 3; ++i) { iou_off[i] = off; off += (size_t)n[i] * 4; }

    for (int i = 0; i < 3; ++i) {
        Layer& L = A.L[i];
        L.pred = (const float*)d_in[8 * i + 0];
        L.b    = (const int*)  d_in[8 * i + 1];
        L.a    = (const int*)  d_in[8 * i + 2];
        L.gj   = (const int*)  d_in[8 * i + 3];
        L.gi   = (const int*)  d_in[8 * i + 4];
        L.tbox = (const float*)d_in[8 * i + 5];
        L.tcls = (const int*)  d_in[8 * i + 6];
        L.anc  = (const float*)d_in[8 * i + 7];
        L.winner = (unsigned int*)(ws + winner_off[i]);
        L.cnt    = (unsigned int*)(ws + cnt_off[i]);
        L.iou    = (float*)(ws + iou_off[i]);
        L.g = g[i];
        L.n = n[i];
    }
    float* acc = (float*)ws;

    hipMemsetAsync(d_ws, 0, zero_bytes, stream);

    // entry kernel: CIoU + scatter winner/cnt + tcls gather
    {
        int b0 = (n[0] + 255) / 256, b1 = (n[1] + 255) / 256, b2 = (n[2] + 255) / 256;
        A.cum0 = b0; A.cum1 = b0 + b1;
        entry_kernel<<<b0 + b1 + b2, 256, 0, stream>>>(A, acc);
    }
    // scan kernel: obj + cls in one coalesced pass (16 floats/thread)
    {
        const int grain = 256 * 16;
        int t0 = BS * NA * 81 * g[0] * g[0];
        int t1 = BS * NA * 81 * g[1] * g[1];
        int t2 = BS * NA * 81 * g[2] * g[2];
        int b0 = (t0 + grain - 1) / grain;
        int b1 = (t1 + grain - 1) / grain;
        int b2 = (t2 + grain - 1) / grain;
        A.cum0 = b0; A.cum1 = b0 + b1;
        scan_kernel<<<b0 + b1 + b2, 256, 0, stream>>>(A, acc);
    }
    final_kernel<<<1, 1, 0, stream>>>(acc, (float*)d_out,
                                      n[0], n[1], n[2],
                                      cells[0], cells[1], cells[2]);
}

// Round 4
// 226.878 us; speedup vs baseline: 1.4082x; 1.3328x over previous
//
#include <hip/hip_runtime.h>
#include <math.h>

// ---------------------------------------------------------------------------
// YOLOv5-style loss, 3 layers, fp32.
// R4: scan was vector-memory-transaction-bound (VALU 12%, HBM 6%): lane-
// stride-64B loads touched 64 lines/instruction and cnt was re-read per
// class plane (129 MB through L1/L2). New structure: thread owns 4 spatial
// cells, loads cnt/winner ONCE, loops channels 4..84 with wave-contiguous
// 1KB loads (16 lines/instr). Per-lane cnt==0 skips all 80 class loads.
// ---------------------------------------------------------------------------

#define EPS 1e-7f
#define BS 16
#define NA 3
#define NC 80

#define LOG2E 1.44269504088896340736f
#define LN2   0.69314718055994530942f

struct Layer {
    const float* pred;
    const int*   b;
    const int*   a;
    const int*   gj;
    const int*   gi;
    const int*   tcls;
    const float* tbox;
    const float* anc;
    unsigned int* winner;   // [48*g*g] cells, 0 = empty else entry_idx+1
    unsigned int* cnt;      // [48*g*g] entry multiplicity per cell
    float*        iou;      // [n] CIoU per entry
    int g;
    int n;
};

struct Args {
    Layer L[3];
    int cum0;   // blocks of layer 0
    int cum1;   // blocks of layers 0+1
};

__device__ __forceinline__ int pick_layer(const Args& A, int& lb) {
    int bid = blockIdx.x;
    if (bid < A.cum0) { lb = bid; return 0; }
    if (bid < A.cum1) { lb = bid - A.cum0; return 1; }
    lb = bid - A.cum1; return 2;
}

// reduce two independent sums across a 256-thread block
__device__ __forceinline__ void block_reduce256_2(float& a, float& b) {
    #pragma unroll
    for (int o = 32; o > 0; o >>= 1) {
        a += __shfl_down(a, o, 64);
        b += __shfl_down(b, o, 64);
    }
    __shared__ float sma[4], smb[4];
    int lane = threadIdx.x & 63;
    int wid  = threadIdx.x >> 6;
    if (lane == 0) { sma[wid] = a; smb[wid] = b; }
    __syncthreads();
    if (threadIdx.x == 0) {
        a = sma[0] + sma[1] + sma[2] + sma[3];
        b = smb[0] + smb[1] + smb[2] + smb[3];
    }
}

// bce_with_logits(x, 0) via HW transcendentals: branchless, ~7 VALU ops
__device__ __forceinline__ float bce0(float x) {
    float t = __builtin_amdgcn_exp2f(-fabsf(x) * LOG2E);   // exp(-|x|)
    return fmaxf(x, 0.f) + LN2 * __builtin_amdgcn_logf(1.f + t);
}

// sigmoid via HW exp2 + rcp
__device__ __forceinline__ float fsigmoid(float x) {
    float e = __builtin_amdgcn_exp2f(-x * LOG2E);
    return __builtin_amdgcn_rcpf(1.f + e);
}

// --- kernel 1: per-entry CIoU + box loss + winner/cnt scatter + tcls gather -
__global__ void entry_kernel(Args A, float* acc) {
    int lb; int layer = pick_layer(A, lb);
    const Layer L = A.L[layer];
    int j = lb * 256 + (int)threadIdx.x;
    float box_c = 0.f;
    float neg_c = 0.f;    // x[tcls] to subtract from cls sum
    if (j < L.n) {
        int b  = L.b[j],  a  = L.a[j];
        int gy = L.gj[j], gx = L.gi[j];
        int g = L.g, gg = g * g;
        int q = b * NA + a;
        const float* base = L.pred + ((size_t)(q * 85) * gg + (size_t)gy * g + gx);
        float px = base[0];
        float py = base[gg];
        float pw = base[2 * (size_t)gg];
        float ph = base[3 * (size_t)gg];
        // decode
        float cx = 2.f * fsigmoid(px) - 0.5f;
        float cy = 2.f * fsigmoid(py) - 0.5f;
        float sw = 2.f * fsigmoid(pw);
        float sh = 2.f * fsigmoid(ph);
        float bw = sw * sw * L.anc[2 * j];
        float bh = sh * sh * L.anc[2 * j + 1];
        float fg = (float)g;
        float tx = L.tbox[4 * j + 0] * fg - (float)gx;
        float ty = L.tbox[4 * j + 1] * fg - (float)gy;
        float tw = L.tbox[4 * j + 2] * fg;
        float th = L.tbox[4 * j + 3] * fg;
        // CIoU
        float b1x1 = cx - bw * 0.5f, b1x2 = cx + bw * 0.5f;
        float b1y1 = cy - bh * 0.5f, b1y2 = cy + bh * 0.5f;
        float b2x1 = tx - tw * 0.5f, b2x2 = tx + tw * 0.5f;
        float b2y1 = ty - th * 0.5f, b2y2 = ty + th * 0.5f;
        float iw = fminf(b1x2, b2x2) - fmaxf(b1x1, b2x1);
        float ih = fminf(b1y2, b2y2) - fmaxf(b1y1, b2y1);
        float inter = fmaxf(iw, 0.f) * fmaxf(ih, 0.f);
        float w1 = b1x2 - b1x1, h1 = b1y2 - b1y1 + EPS;
        float w2 = b2x2 - b2x1, h2 = b2y2 - b2y1 + EPS;
        float uni = w1 * h1 + w2 * h2 - inter + EPS;
        float iou = inter / uni;
        float cw  = fmaxf(b1x2, b2x2) - fminf(b1x1, b2x1);
        float chh = fmaxf(b1y2, b2y2) - fminf(b1y1, b2y1);
        float c2  = cw * cw + chh * chh + EPS;
        float dx = b2x1 + b2x2 - b1x1 - b1x2;
        float dy = b2y1 + b2y2 - b1y1 - b1y2;
        float rho2 = (dx * dx + dy * dy) * 0.25f;
        float dv = atanf(w2 / h2) - atanf(w1 / h1);
        float v = (4.f / (float)(M_PI * M_PI)) * dv * dv;
        float alpha = v / (v - iou + (1.f + EPS));
        float ciou = iou - (rho2 / c2 + v * alpha);
        L.iou[j] = ciou;
        int cell = q * gg + gy * g + gx;
        atomicMax(&L.winner[cell], (unsigned int)(j + 1));
        atomicAdd(&L.cnt[cell], 1u);
        box_c = 1.f - ciou;
        // class positive term: bce(x,1) = bce(x,0) - x  -> subtract x[tcls]
        neg_c = base[(size_t)(5 + L.tcls[j]) * gg];
    }
    block_reduce256_2(box_c, neg_c);
    if (threadIdx.x == 0) {
        atomicAdd(&acc[0 + layer], box_c);
        atomicAdd(&acc[6 + layer], -neg_c);
    }
}

// --- kernel 2: channel-loop scan ------------------------------------------
// Thread owns 4 consecutive spatial cells (one float4 column), loads
// cnt/winner once, then walks channels 4..84 at stride gg. Every pred load
// is wave-contiguous (64 lanes x 16B = 1KB). Block covers 1024 cells.
__global__ void scan_kernel(Args A, float* acc) {
    int lb; int layer = pick_layer(A, lb);
    const Layer L = A.L[layer];
    int gg = L.g * L.g;
    int cells = BS * NA * gg;
    int ci = lb * 1024 + (int)threadIdx.x * 4;
    float obj_s = 0.f, cls_s = 0.f;
    if (ci < cells) {
        int q = ci / gg;
        int e = ci - q * gg;
        uint4 c4 = *(const uint4*)(L.cnt + ci);
        uint4 w4 = *(const uint4*)(L.winner + ci);
        const float* pbase = L.pred + (size_t)(q * 85 + 4) * gg + e;
        float4 x4 = *(const float4*)pbase;           // objectness channel
        obj_s = bce0(x4.x) + bce0(x4.y) + bce0(x4.z) + bce0(x4.w);
        if (w4.x) obj_s -= x4.x * fmaxf(L.iou[w4.x - 1], 0.f);
        if (w4.y) obj_s -= x4.y * fmaxf(L.iou[w4.y - 1], 0.f);
        if (w4.z) obj_s -= x4.z * fmaxf(L.iou[w4.z - 1], 0.f);
        if (w4.w) obj_s -= x4.w * fmaxf(L.iou[w4.w - 1], 0.f);
        if (c4.x | c4.y | c4.z | c4.w) {
            float f0 = (float)c4.x, f1 = (float)c4.y;
            float f2 = (float)c4.z, f3 = (float)c4.w;
            const float* p = pbase + gg;
            #pragma unroll 8
            for (int r = 0; r < NC; ++r) {
                float4 y = *(const float4*)(p + (size_t)r * gg);
                cls_s += f0 * bce0(y.x) + f1 * bce0(y.y)
                       + f2 * bce0(y.z) + f3 * bce0(y.w);
            }
        }
    }
    block_reduce256_2(obj_s, cls_s);
    if (threadIdx.x == 0) {
        if (obj_s != 0.f) atomicAdd(&acc[3 + layer], obj_s);
        if (cls_s != 0.f) atomicAdd(&acc[6 + layer], cls_s);
    }
}

// --- kernel 3: combine ------------------------------------------------------
__global__ void final_kernel(const float* acc, float* out,
                             int n0, int n1, int n2,
                             int c0, int c1, int c2) {
    float box_l = acc[0] / (float)n0 + acc[1] / (float)n1 + acc[2] / (float)n2;
    float obj_l = 0.4f * acc[3] / (float)c0
                + 1.0f * acc[4] / (float)c1
                + 4.0f * acc[5] / (float)c2;
    float cls_l = acc[6] / ((float)n0 * NC)
                + acc[7] / ((float)n1 * NC)
                + acc[8] / ((float)n2 * NC);
    out[0] = 0.05f * box_l + 1.0f * obj_l + 0.5f * cls_l;
}

extern "C" void kernel_launch(void* const* d_in, const int* in_sizes, int n_in,
                              void* d_out, int out_size, void* d_ws, size_t ws_size,
                              hipStream_t stream) {
    (void)n_in; (void)out_size; (void)ws_size;
    char* ws = (char*)d_ws;

    Args A;
    int n[3], g[3], cells[3];
    size_t off = 64;                       // bytes 0..63: 9 float accumulators
    size_t winner_off[3], cnt_off[3], iou_off[3];

    for (int i = 0; i < 3; ++i) {
        n[i] = in_sizes[8 * i + 1];
        int gg = in_sizes[8 * i] / (BS * 255);
        int gv = (int)(sqrt((double)gg) + 0.5);
        g[i] = gv;
        cells[i] = BS * NA * gv * gv;
        winner_off[i] = off; off += (size_t)cells[i] * 4;
        cnt_off[i]    = off; off += (size_t)cells[i] * 4;
    }
    size_t zero_bytes = off;               // accumulators + winner + cnt
    for (int i = 0; i < 3; ++i) { iou_off[i] = off; off += (size_t)n[i] * 4; }

    for (int i = 0; i < 3; ++i) {
        Layer& L = A.L[i];
        L.pred = (const float*)d_in[8 * i + 0];
        L.b    = (const int*)  d_in[8 * i + 1];
        L.a    = (const int*)  d_in[8 * i + 2];
        L.gj   = (const int*)  d_in[8 * i + 3];
        L.gi   = (const int*)  d_in[8 * i + 4];
        L.tbox = (const float*)d_in[8 * i + 5];
        L.tcls = (const int*)  d_in[8 * i + 6];
        L.anc  = (const float*)d_in[8 * i + 7];
        L.winner = (unsigned int*)(ws + winner_off[i]);
        L.cnt    = (unsigned int*)(ws + cnt_off[i]);
        L.iou    = (float*)(ws + iou_off[i]);
        L.g = g[i];
        L.n = n[i];
    }
    float* acc = (float*)ws;

    hipMemsetAsync(d_ws, 0, zero_bytes, stream);

    // entry kernel: CIoU + scatter winner/cnt + tcls gather
    {
        int b0 = (n[0] + 255) / 256, b1 = (n[1] + 255) / 256, b2 = (n[2] + 255) / 256;
        A.cum0 = b0; A.cum1 = b0 + b1;
        entry_kernel<<<b0 + b1 + b2, 256, 0, stream>>>(A, acc);
    }
    // scan kernel: 1024 cells per block, channel loop inside
    {
        int b0 = (cells[0] + 1023) / 1024;
        int b1 = (cells[1] + 1023) / 1024;
        int b2 = (cells[2] + 1023) / 1024;
        A.cum0 = b0; A.cum1 = b0 + b1;
        scan_kernel<<<b0 + b1 + b2, 256, 0, stream>>>(A, acc);
    }
    final_kernel<<<1, 1, 0, stream>>>(acc, (float*)d_out,
                                      n[0], n[1], n[2],
                                      cells[0], cells[1], cells[2]);
}